// Round 1
// baseline (379.591 us; speedup 1.0000x reference)
//
#include <hip/hip_runtime.h>
#include <hip/hip_bf16.h>

#define NB 128      // batch
#define NT 128      // Tm1
#define ND 128      // input size (drivers)
#define NH 64       // hidden
#define NTH 1024    // threads per block
#define ESTR 144    // Ebt row stride (ushorts), 16B-aligned rows, 2-way-max banks

__device__ __forceinline__ float fexp2(float x) { return __builtin_amdgcn_exp2f(x); }
__device__ __forceinline__ float frcp (float x) { return __builtin_amdgcn_rcpf(x); }

// f32 -> bf16 bits, round-to-nearest-even
__device__ __forceinline__ unsigned short f2bf(float f) {
  unsigned u = __float_as_uint(f);
  u += 0x7fffu + ((u >> 16) & 1u);
  return (unsigned short)(u >> 16);
}

__global__ __launch_bounds__(NTH) void darnn_enc(
    const float* __restrict__ x,     // [B][T1][D]
    const float* __restrict__ Wehs,  // [T1][2H] = [128][128]
    const float* __restrict__ behs,  // [T1]
    const float* __restrict__ Ue,    // [T1][T1] (s,t)
    const float* __restrict__ Ueb,   // [T1]
    const float* __restrict__ vew,   // [T1]
    const float* __restrict__ Wih,   // [4H][D] = [256][128]
    const float* __restrict__ Whh,   // [4H][H] = [256][64]
    const float* __restrict__ bih,   // [256]
    const float* __restrict__ bhh,   // [256]
    float* __restrict__ out)         // [B*T1*D] weighted ++ [B*T1*H] encoded
{
  constexpr float C2  = 2.88539008177792681f;  // 2*log2(e)
  constexpr float L2E = 1.44269504088896340f;  // log2(e)

  __shared__ __align__(16) float          UeTc[128][33];      // staged Ue^T chunk
  __shared__ __align__(16) unsigned short Ebt[128][ESTR];     // E[d][s] bf16
  __shared__ __align__(16) float          hc[128];            // [h | c]
  __shared__ __align__(16) float          wvs[128];           // w_s = exp(2*we_s)
  __shared__ __align__(16) float          smv[128];           // v[d]
  __shared__ __align__(16) float          gates[256];
  __shared__ __align__(16) float          xrep[4][132];       // x_hat replicas
  __shared__ __align__(16) float          hrep[4][68];        // h replicas

  const int b    = blockIdx.x;
  const int tid  = threadIdx.x;
  const int lane = tid & 63;
  const int wid  = tid >> 6;
  const float* xb = x + b * (NT * ND);

  // ---------------- Prologue: E[d][s] = exp(2*(x_perm @ Ue^T + Ueb)) --------
  {
    const int dq = tid & 31;   // d-quad index: d in [4dq, 4dq+4)
    const int sg = tid >> 5;   // s within 32-chunk
    float acc[16];
#pragma unroll
    for (int i = 0; i < 16; ++i) acc[i] = 0.f;
    for (int c = 0; c < 4; ++c) {
      {  // stage UeTc[t][s_local] = Ue[32c+s_local][t]
        const int ss = 32 * c + sg;
        const int t4 = dq * 4;
        const float4 u4 = *reinterpret_cast<const float4*>(Ue + ss * NT + t4);
        UeTc[t4 + 0][sg] = u4.x;
        UeTc[t4 + 1][sg] = u4.y;
        UeTc[t4 + 2][sg] = u4.z;
        UeTc[t4 + 3][sg] = u4.w;
      }
      __syncthreads();
#pragma unroll 4
      for (int t = 0; t < NT; ++t) {
        const float4 xv = *reinterpret_cast<const float4*>(xb + t * ND + 4 * dq);
        const float u = UeTc[t][sg];
        acc[4*c+0] = fmaf(xv.x, u, acc[4*c+0]);
        acc[4*c+1] = fmaf(xv.y, u, acc[4*c+1]);
        acc[4*c+2] = fmaf(xv.z, u, acc[4*c+2]);
        acc[4*c+3] = fmaf(xv.w, u, acc[4*c+3]);
      }
      __syncthreads();
    }
#pragma unroll
    for (int c = 0; c < 4; ++c) {
      const int ss = sg + 32 * c;
      const float ub = Ueb[ss];
#pragma unroll
      for (int di = 0; di < 4; ++di) {
        const float e = fexp2(C2 * (acc[4*c+di] + ub));
        Ebt[4*dq + di][ss] = f2bf(e);
      }
    }
  }

  if (tid < 128) hc[tid] = 0.f;
  if (tid < 64) {
#pragma unroll
    for (int q = 0; q < 4; ++q) hrep[q][tid] = 0.f;
  }

  // ---------------- persistent per-thread weight registers ------------------
  // phase A: 8 threads per s
  const int s_a = tid >> 3, r_a = tid & 7;
  float wehs_r[16];
#pragma unroll
  for (int i = 0; i < 4; ++i) {
    const float4 v4 = *reinterpret_cast<const float4*>(Wehs + s_a * 128 + r_a * 16 + 4 * i);
    wehs_r[4*i+0] = v4.x; wehs_r[4*i+1] = v4.y; wehs_r[4*i+2] = v4.z; wehs_r[4*i+3] = v4.w;
  }
  const float behs_r = behs[s_a];

  // phase B: lane decomposition
  const int s_l = lane & 15;
  const int dp  = lane >> 4;
  const int d0  = 8 * wid + 2 * dp;
  float m2vw[8];
  {
    const float4 va = *reinterpret_cast<const float4*>(vew + 8 * s_l);
    const float4 vb = *reinterpret_cast<const float4*>(vew + 8 * s_l + 4);
    m2vw[0] = -2.f * va.x; m2vw[1] = -2.f * va.y; m2vw[2] = -2.f * va.z; m2vw[3] = -2.f * va.w;
    m2vw[4] = -2.f * vb.x; m2vw[5] = -2.f * vb.y; m2vw[6] = -2.f * vb.z; m2vw[7] = -2.f * vb.w;
  }

  // phase D: 4 threads per gate
  const int j_d = tid >> 2, q_d = tid & 3;
  float wih_r[32];
#pragma unroll
  for (int i = 0; i < 8; ++i) {
    const float4 v4 = *reinterpret_cast<const float4*>(Wih + j_d * 128 + 32 * q_d + 4 * i);
    wih_r[4*i+0] = v4.x; wih_r[4*i+1] = v4.y; wih_r[4*i+2] = v4.z; wih_r[4*i+3] = v4.w;
  }
  float whh_r[16];
#pragma unroll
  for (int i = 0; i < 4; ++i) {
    const float4 v4 = *reinterpret_cast<const float4*>(Whh + j_d * 64 + 16 * q_d + 4 * i);
    whh_r[4*i+0] = v4.x; whh_r[4*i+1] = v4.y; whh_r[4*i+2] = v4.z; whh_r[4*i+3] = v4.w;
  }
  const float bias_d = bih[j_d] + bhh[j_d];

  __syncthreads();

  // ---------------- main recurrence over time -------------------------------
  for (int t = 0; t < NT; ++t) {
    // prefetch x_t for phase C (latency hidden under A+B)
    float xt0 = 0.f, xt1 = 0.f;
    if (wid == 0) { xt0 = xb[t * ND + lane]; xt1 = xb[t * ND + lane + 64]; }

    // ---- A: we[s] = behs[s] + hc . Wehs[s,:];  w_s = exp(2*we)
    {
      float a0 = 0.f;
#pragma unroll
      for (int i = 0; i < 4; ++i) {
        const float4 h4 = *reinterpret_cast<const float4*>(hc + 16 * r_a + 4 * i);
        a0 = fmaf(h4.x, wehs_r[4*i+0], a0);
        a0 = fmaf(h4.y, wehs_r[4*i+1], a0);
        a0 = fmaf(h4.z, wehs_r[4*i+2], a0);
        a0 = fmaf(h4.w, wehs_r[4*i+3], a0);
      }
      a0 += __shfl_xor(a0, 1); a0 += __shfl_xor(a0, 2); a0 += __shfl_xor(a0, 4);
      if (r_a == 0) wvs[s_a] = fexp2(C2 * (a0 + behs_r));
    }
    __syncthreads();

    // ---- B: v[d] = sum_s (-2 vw[s]) / (1 + w_s * E[d][s])   (+ const, dropped)
    {
      const float4 wa = *reinterpret_cast<const float4*>(wvs + 8 * s_l);
      const float4 wb = *reinterpret_cast<const float4*>(wvs + 8 * s_l + 4);
      const int4 ea = *reinterpret_cast<const int4*>(&Ebt[d0][8 * s_l]);
      const int4 eb = *reinterpret_cast<const int4*>(&Ebt[d0 + 1][8 * s_l]);
      float a0 = 0.f, a1 = 0.f;
      unsigned w;
      w = (unsigned)ea.x;
      a0 = fmaf(m2vw[0], frcp(fmaf(wa.x, __uint_as_float(w << 16), 1.f)), a0);
      a0 = fmaf(m2vw[1], frcp(fmaf(wa.y, __uint_as_float(w & 0xffff0000u), 1.f)), a0);
      w = (unsigned)ea.y;
      a0 = fmaf(m2vw[2], frcp(fmaf(wa.z, __uint_as_float(w << 16), 1.f)), a0);
      a0 = fmaf(m2vw[3], frcp(fmaf(wa.w, __uint_as_float(w & 0xffff0000u), 1.f)), a0);
      w = (unsigned)ea.z;
      a0 = fmaf(m2vw[4], frcp(fmaf(wb.x, __uint_as_float(w << 16), 1.f)), a0);
      a0 = fmaf(m2vw[5], frcp(fmaf(wb.y, __uint_as_float(w & 0xffff0000u), 1.f)), a0);
      w = (unsigned)ea.w;
      a0 = fmaf(m2vw[6], frcp(fmaf(wb.z, __uint_as_float(w << 16), 1.f)), a0);
      a0 = fmaf(m2vw[7], frcp(fmaf(wb.w, __uint_as_float(w & 0xffff0000u), 1.f)), a0);
      w = (unsigned)eb.x;
      a1 = fmaf(m2vw[0], frcp(fmaf(wa.x, __uint_as_float(w << 16), 1.f)), a1);
      a1 = fmaf(m2vw[1], frcp(fmaf(wa.y, __uint_as_float(w & 0xffff0000u), 1.f)), a1);
      w = (unsigned)eb.y;
      a1 = fmaf(m2vw[2], frcp(fmaf(wa.z, __uint_as_float(w << 16), 1.f)), a1);
      a1 = fmaf(m2vw[3], frcp(fmaf(wa.w, __uint_as_float(w & 0xffff0000u), 1.f)), a1);
      w = (unsigned)eb.z;
      a1 = fmaf(m2vw[4], frcp(fmaf(wb.x, __uint_as_float(w << 16), 1.f)), a1);
      a1 = fmaf(m2vw[5], frcp(fmaf(wb.y, __uint_as_float(w & 0xffff0000u), 1.f)), a1);
      w = (unsigned)eb.w;
      a1 = fmaf(m2vw[6], frcp(fmaf(wb.z, __uint_as_float(w << 16), 1.f)), a1);
      a1 = fmaf(m2vw[7], frcp(fmaf(wb.w, __uint_as_float(w & 0xffff0000u), 1.f)), a1);
#pragma unroll
      for (int m = 1; m < 16; m <<= 1) { a0 += __shfl_xor(a0, m); a1 += __shfl_xor(a1, m); }
      if (s_l == 0) { smv[d0] = a0; smv[d0 + 1] = a1; }
    }
    __syncthreads();

    // ---- C: softmax over d, x_hat = a * x_t  (wave 0)
    if (wid == 0) {
      const float v0 = smv[lane], v1 = smv[lane + 64];
      float mx = fmaxf(v0, v1);
#pragma unroll
      for (int m = 1; m < 64; m <<= 1) mx = fmaxf(mx, __shfl_xor(mx, m));
      const float e0 = fexp2(L2E * (v0 - mx));
      const float e1 = fexp2(L2E * (v1 - mx));
      float sum = e0 + e1;
#pragma unroll
      for (int m = 1; m < 64; m <<= 1) sum += __shfl_xor(sum, m);
      const float rs = frcp(sum);
      const float xh0 = e0 * rs * xt0;
      const float xh1 = e1 * rs * xt1;
#pragma unroll
      for (int q = 0; q < 4; ++q) { xrep[q][lane] = xh0; xrep[q][lane + 64] = xh1; }
      out[b * (NT * ND) + t * ND + lane]      = xh0;
      out[b * (NT * ND) + t * ND + lane + 64] = xh1;
    }
    __syncthreads();

    // ---- D: gates[j] = bias + x_hat . Wih[j,:] + h . Whh[j,:]
    {
      float a = 0.f;
      const float* xr = &xrep[q_d][32 * q_d];
#pragma unroll
      for (int i = 0; i < 8; ++i) {
        const float4 v4 = *reinterpret_cast<const float4*>(xr + 4 * i);
        a = fmaf(v4.x, wih_r[4*i+0], a);
        a = fmaf(v4.y, wih_r[4*i+1], a);
        a = fmaf(v4.z, wih_r[4*i+2], a);
        a = fmaf(v4.w, wih_r[4*i+3], a);
      }
      const float* hr = &hrep[q_d][16 * q_d];
#pragma unroll
      for (int i = 0; i < 4; ++i) {
        const float4 v4 = *reinterpret_cast<const float4*>(hr + 4 * i);
        a = fmaf(v4.x, whh_r[4*i+0], a);
        a = fmaf(v4.y, whh_r[4*i+1], a);
        a = fmaf(v4.z, whh_r[4*i+2], a);
        a = fmaf(v4.w, whh_r[4*i+3], a);
      }
      a += __shfl_xor(a, 1);
      a += __shfl_xor(a, 2);
      if (q_d == 0) gates[j_d] = a + bias_d;
    }
    __syncthreads();

    // ---- E: LSTM cell update (wave 0, 64 lanes = H)
    if (wid == 0) {
      const int k = lane;
      const float gi = gates[k];
      const float gf = gates[64 + k];
      const float gg = gates[128 + k];
      const float go = gates[192 + k];
      const float c_old = hc[64 + k];
      const float si = frcp(1.f + fexp2(-L2E * gi));
      const float sf = frcp(1.f + fexp2(-L2E * gf));
      const float tg = 1.f - 2.f * frcp(1.f + fexp2(C2 * gg));
      const float cn = fmaf(sf, c_old, si * tg);
      const float so = frcp(1.f + fexp2(-L2E * go));
      const float tc = 1.f - 2.f * frcp(1.f + fexp2(C2 * cn));
      const float hn = so * tc;
      hc[k] = hn;
      hc[64 + k] = cn;
#pragma unroll
      for (int q = 0; q < 4; ++q) hrep[q][k] = hn;
      out[NB * NT * ND + b * (NT * NH) + t * NH + k] = hn;
    }
    __syncthreads();
  }
}

extern "C" void kernel_launch(void* const* d_in, const int* in_sizes, int n_in,
                              void* d_out, int out_size, void* d_ws, size_t ws_size,
                              hipStream_t stream) {
  const float* x    = (const float*)d_in[0];
  const float* Wehs = (const float*)d_in[1];
  const float* behs = (const float*)d_in[2];
  const float* Ue   = (const float*)d_in[3];
  const float* Ueb  = (const float*)d_in[4];
  const float* vew  = (const float*)d_in[5];
  // d_in[6] = v_e_b: adds a constant to v before softmax -> no effect, unused.
  const float* Wih  = (const float*)d_in[7];
  const float* Whh  = (const float*)d_in[8];
  const float* bih  = (const float*)d_in[9];
  const float* bhh  = (const float*)d_in[10];
  float* out = (float*)d_out;

  darnn_enc<<<NB, NTH, 0, stream>>>(x, Wehs, behs, Ue, Ueb, vew, Wih, Whh, bih, bhh, out);
}

// Round 2
// 356.700 us; speedup vs baseline: 1.0642x; 1.0642x over previous
//
#include <hip/hip_runtime.h>
#include <hip/hip_bf16.h>

#define NB 128      // batch
#define NT 128      // Tm1
#define ND 128      // input size (drivers)
#define NH 64       // hidden
#define NTH 1024    // threads per block
#define ESTR 144    // Ebt row stride (ushorts): uniform bank coverage for b128 reads

__device__ __forceinline__ float fexp2(float x) { return __builtin_amdgcn_exp2f(x); }
__device__ __forceinline__ float frcp (float x) { return __builtin_amdgcn_rcpf(x); }

// f32 -> bf16 bits, round-to-nearest-even
__device__ __forceinline__ unsigned short f2bf(float f) {
  unsigned u = __float_as_uint(f);
  u += 0x7fffu + ((u >> 16) & 1u);
  return (unsigned short)(u >> 16);
}

__global__ __launch_bounds__(NTH) void darnn_enc(
    const float* __restrict__ x,     // [B][T1][D]
    const float* __restrict__ Wehs,  // [T1][2H] = [128][128]
    const float* __restrict__ behs,  // [T1]
    const float* __restrict__ Ue,    // [T1][T1] (s,t)
    const float* __restrict__ Ueb,   // [T1]
    const float* __restrict__ vew,   // [T1]
    const float* __restrict__ Wih,   // [4H][D] = [256][128]
    const float* __restrict__ Whh,   // [4H][H] = [256][64]
    const float* __restrict__ bih,   // [256]
    const float* __restrict__ bhh,   // [256]
    float* __restrict__ out)         // [B*T1*D] weighted ++ [B*T1*H] encoded
{
  constexpr float C2  = 2.88539008177792681f;  // 2*log2(e)
  constexpr float L2E = 1.44269504088896340f;  // log2(e)

  // ---- LDS (~142 KB total; 1 block/CU, which is structural anyway) ----
  __shared__ __align__(16) float          xh[NT][ND];       // 65536: x, overwritten by x_hat
  __shared__ __align__(16) unsigned short Ebt[ND][ESTR];    // 36864: E[d][s] bf16
  __shared__ __align__(16) float          hbuf[NT][NH];     // 32768: h outputs (prologue: UeTc)
  __shared__ __align__(16) float          hcp[2][8][20];    // 1280: [h|c] chunked+padded, dbuf
  __shared__ __align__(16) float          hrep[2][4][68];   // 2176: h replicas for gate GEMV, dbuf
  __shared__ __align__(16) float          wvp[16][12];      // 768: w_s = exp(2*we) chunked+padded
  __shared__ __align__(16) float          smv[128];         // 512: v[d]
  __shared__ __align__(16) float          xrep[4][132];     // 2112: x_hat replicas

  const int b    = blockIdx.x;
  const int tid  = threadIdx.x;
  const int lane = tid & 63;
  const int wid  = tid >> 6;
  const float* xb = x + b * (NT * ND);

  // ---------------- stage x into LDS (read once from global) ---------------
#pragma unroll
  for (int i = 0; i < 4; ++i) {
    const int f = i * 1024 + tid;          // float4 index
    const int t = f >> 5, c = (f & 31) << 2;
    *reinterpret_cast<float4*>(&xh[t][c]) =
        *reinterpret_cast<const float4*>(xb + t * ND + c);
  }
  float (*UeTc)[33] = reinterpret_cast<float(*)[33]>(&hbuf[0][0]);  // prologue-only overlay
  __syncthreads();

  // ---------------- Prologue: E[d][s] = exp(2*(x_perm @ Ue^T + Ueb)) --------
  {
    const int dq = tid & 31;   // d-quad: d in [4dq, 4dq+4)
    const int sg = tid >> 5;   // s within 32-chunk
    float acc[16];
#pragma unroll
    for (int i = 0; i < 16; ++i) acc[i] = 0.f;
    for (int c = 0; c < 4; ++c) {
      {  // stage UeTc[t][s_local] = Ue[32c+s_local][t]
        const int ss = 32 * c + sg;
        const int t4 = dq * 4;
        const float4 u4 = *reinterpret_cast<const float4*>(Ue + ss * NT + t4);
        UeTc[t4 + 0][sg] = u4.x;
        UeTc[t4 + 1][sg] = u4.y;
        UeTc[t4 + 2][sg] = u4.z;
        UeTc[t4 + 3][sg] = u4.w;
      }
      __syncthreads();
#pragma unroll 4
      for (int t = 0; t < NT; ++t) {
        const float4 xv = *reinterpret_cast<const float4*>(&xh[t][4 * dq]);
        const float u = UeTc[t][sg];
        acc[4*c+0] = fmaf(xv.x, u, acc[4*c+0]);
        acc[4*c+1] = fmaf(xv.y, u, acc[4*c+1]);
        acc[4*c+2] = fmaf(xv.z, u, acc[4*c+2]);
        acc[4*c+3] = fmaf(xv.w, u, acc[4*c+3]);
      }
      __syncthreads();
    }
#pragma unroll
    for (int c = 0; c < 4; ++c) {
      const int ss = sg + 32 * c;
      const float ub = Ueb[ss];
#pragma unroll
      for (int di = 0; di < 4; ++di) {
        const float e = fexp2(C2 * (acc[4*c+di] + ub));
        Ebt[4*dq + di][ss] = f2bf(e);
      }
    }
  }

  // init h/c state (both parity buffers) to zero
  {
    float* z1 = &hcp[0][0][0];
    if (tid < 320) z1[tid] = 0.f;
    float* z2 = &hrep[0][0][0];
    if (tid < 544) z2[tid] = 0.f;
  }

  // ---------------- persistent per-thread weight registers ------------------
  // phase A: 8 threads per s
  const int s_a = tid >> 3, r_a = tid & 7;
  const int g_a = s_a >> 3, c_a = s_a & 7;
  float wehs_r[16];
#pragma unroll
  for (int i = 0; i < 4; ++i) {
    const float4 v4 = *reinterpret_cast<const float4*>(Wehs + s_a * 128 + r_a * 16 + 4 * i);
    wehs_r[4*i+0] = v4.x; wehs_r[4*i+1] = v4.y; wehs_r[4*i+2] = v4.z; wehs_r[4*i+3] = v4.w;
  }
  const float behs_r = behs[s_a];

  // phase B: lane decomposition
  const int s_l = lane & 15;
  const int dp  = lane >> 4;
  const int d0  = 8 * wid + 2 * dp;
  float m2vw[8];
  {
    const float4 va = *reinterpret_cast<const float4*>(vew + 8 * s_l);
    const float4 vb = *reinterpret_cast<const float4*>(vew + 8 * s_l + 4);
    m2vw[0] = -2.f * va.x; m2vw[1] = -2.f * va.y; m2vw[2] = -2.f * va.z; m2vw[3] = -2.f * va.w;
    m2vw[4] = -2.f * vb.x; m2vw[5] = -2.f * vb.y; m2vw[6] = -2.f * vb.z; m2vw[7] = -2.f * vb.w;
  }

  // phase D+E fused: lane = 16*kk + 4*gate + quarter
  const int kk = lane >> 4, gg = (lane >> 2) & 3, qq = lane & 3;
  const int k_de = 4 * wid + kk;          // hidden unit
  const int j_de = 64 * gg + k_de;        // gate row
  float wih_r[32];
#pragma unroll
  for (int i = 0; i < 8; ++i) {
    const float4 v4 = *reinterpret_cast<const float4*>(Wih + j_de * 128 + 32 * qq + 4 * i);
    wih_r[4*i+0] = v4.x; wih_r[4*i+1] = v4.y; wih_r[4*i+2] = v4.z; wih_r[4*i+3] = v4.w;
  }
  float whh_r[16];
#pragma unroll
  for (int i = 0; i < 4; ++i) {
    const float4 v4 = *reinterpret_cast<const float4*>(Whh + j_de * 64 + 16 * qq + 4 * i);
    whh_r[4*i+0] = v4.x; whh_r[4*i+1] = v4.y; whh_r[4*i+2] = v4.z; whh_r[4*i+3] = v4.w;
  }
  const float bias_de = bih[j_de] + bhh[j_de];

  __syncthreads();

  // ---------------- main recurrence: 4 barriers/step, NO global mem ---------
  int p = 0;  // parity of h/c double buffer
  for (int t = 0; t < NT; ++t) {
    // ---- A: we[s] = behs[s] + hc . Wehs[s,:];  w_s = exp(2*we)
    {
      float a0 = 0.f;
      const float* hp = &hcp[p][r_a][0];
#pragma unroll
      for (int i = 0; i < 4; ++i) {
        const float4 h4 = *reinterpret_cast<const float4*>(hp + 4 * i);
        a0 = fmaf(h4.x, wehs_r[4*i+0], a0);
        a0 = fmaf(h4.y, wehs_r[4*i+1], a0);
        a0 = fmaf(h4.z, wehs_r[4*i+2], a0);
        a0 = fmaf(h4.w, wehs_r[4*i+3], a0);
      }
      a0 += __shfl_xor(a0, 1); a0 += __shfl_xor(a0, 2); a0 += __shfl_xor(a0, 4);
      if (r_a == 0) wvp[g_a][c_a] = fexp2(C2 * (a0 + behs_r));
    }
    __syncthreads();

    // ---- B: v[d] = sum_s (-2 vw[s]) / (1 + w_s * E[d][s])   (+ const, dropped)
    {
      const float4 wa = *reinterpret_cast<const float4*>(&wvp[s_l][0]);
      const float4 wb = *reinterpret_cast<const float4*>(&wvp[s_l][4]);
      const int4 ea = *reinterpret_cast<const int4*>(&Ebt[d0][8 * s_l]);
      const int4 eb = *reinterpret_cast<const int4*>(&Ebt[d0 + 1][8 * s_l]);
      float a0 = 0.f, a1 = 0.f;
      unsigned w;
      w = (unsigned)ea.x;
      a0 = fmaf(m2vw[0], frcp(fmaf(wa.x, __uint_as_float(w << 16), 1.f)), a0);
      a0 = fmaf(m2vw[1], frcp(fmaf(wa.y, __uint_as_float(w & 0xffff0000u), 1.f)), a0);
      w = (unsigned)ea.y;
      a0 = fmaf(m2vw[2], frcp(fmaf(wa.z, __uint_as_float(w << 16), 1.f)), a0);
      a0 = fmaf(m2vw[3], frcp(fmaf(wa.w, __uint_as_float(w & 0xffff0000u), 1.f)), a0);
      w = (unsigned)ea.z;
      a0 = fmaf(m2vw[4], frcp(fmaf(wb.x, __uint_as_float(w << 16), 1.f)), a0);
      a0 = fmaf(m2vw[5], frcp(fmaf(wb.y, __uint_as_float(w & 0xffff0000u), 1.f)), a0);
      w = (unsigned)ea.w;
      a0 = fmaf(m2vw[6], frcp(fmaf(wb.z, __uint_as_float(w << 16), 1.f)), a0);
      a0 = fmaf(m2vw[7], frcp(fmaf(wb.w, __uint_as_float(w & 0xffff0000u), 1.f)), a0);
      w = (unsigned)eb.x;
      a1 = fmaf(m2vw[0], frcp(fmaf(wa.x, __uint_as_float(w << 16), 1.f)), a1);
      a1 = fmaf(m2vw[1], frcp(fmaf(wa.y, __uint_as_float(w & 0xffff0000u), 1.f)), a1);
      w = (unsigned)eb.y;
      a1 = fmaf(m2vw[2], frcp(fmaf(wa.z, __uint_as_float(w << 16), 1.f)), a1);
      a1 = fmaf(m2vw[3], frcp(fmaf(wa.w, __uint_as_float(w & 0xffff0000u), 1.f)), a1);
      w = (unsigned)eb.z;
      a1 = fmaf(m2vw[4], frcp(fmaf(wb.x, __uint_as_float(w << 16), 1.f)), a1);
      a1 = fmaf(m2vw[5], frcp(fmaf(wb.y, __uint_as_float(w & 0xffff0000u), 1.f)), a1);
      w = (unsigned)eb.w;
      a1 = fmaf(m2vw[6], frcp(fmaf(wb.z, __uint_as_float(w << 16), 1.f)), a1);
      a1 = fmaf(m2vw[7], frcp(fmaf(wb.w, __uint_as_float(w & 0xffff0000u), 1.f)), a1);
#pragma unroll
      for (int m = 1; m < 16; m <<= 1) { a0 += __shfl_xor(a0, m); a1 += __shfl_xor(a1, m); }
      if (s_l == 0) { smv[d0] = a0; smv[d0 + 1] = a1; }
    }
    __syncthreads();

    // ---- C: softmax over d (no max-sub: |v|<=~10), x_hat = a*x_t  (wave 0)
    if (wid == 0) {
      const float v0 = smv[lane], v1 = smv[lane + 64];
      const float e0 = fexp2(L2E * v0);
      const float e1 = fexp2(L2E * v1);
      float sum = e0 + e1;
#pragma unroll
      for (int m = 1; m < 64; m <<= 1) sum += __shfl_xor(sum, m);
      const float rs = frcp(sum);
      const float xh0 = e0 * rs * xh[t][lane];
      const float xh1 = e1 * rs * xh[t][lane + 64];
#pragma unroll
      for (int q = 0; q < 4; ++q) { xrep[q][lane] = xh0; xrep[q][lane + 64] = xh1; }
      xh[t][lane]      = xh0;   // in-place: becomes the output buffer
      xh[t][lane + 64] = xh1;
    }
    __syncthreads();

    // ---- D+E fused: gates + LSTM cell, no barrier between
    {
      float a = 0.f;
      const float* xr = &xrep[qq][32 * qq];
#pragma unroll
      for (int i = 0; i < 8; ++i) {
        const float4 v4 = *reinterpret_cast<const float4*>(xr + 4 * i);
        a = fmaf(v4.x, wih_r[4*i+0], a);
        a = fmaf(v4.y, wih_r[4*i+1], a);
        a = fmaf(v4.z, wih_r[4*i+2], a);
        a = fmaf(v4.w, wih_r[4*i+3], a);
      }
      const float* hr = &hrep[p][qq][16 * qq];
#pragma unroll
      for (int i = 0; i < 4; ++i) {
        const float4 v4 = *reinterpret_cast<const float4*>(hr + 4 * i);
        a = fmaf(v4.x, whh_r[4*i+0], a);
        a = fmaf(v4.y, whh_r[4*i+1], a);
        a = fmaf(v4.z, whh_r[4*i+2], a);
        a = fmaf(v4.w, whh_r[4*i+3], a);
      }
      a += __shfl_xor(a, 1);
      a += __shfl_xor(a, 2);
      a += bias_de;
      const int base = 16 * kk;
      const float gi = __shfl(a, base);
      const float gf = __shfl(a, base + 4);
      const float gG = __shfl(a, base + 8);
      const float go = __shfl(a, base + 12);
      const float c_old = hcp[p][4 + (k_de >> 4)][k_de & 15];
      const float si = frcp(1.f + fexp2(-L2E * gi));
      const float sf = frcp(1.f + fexp2(-L2E * gf));
      const float tg = 1.f - 2.f * frcp(1.f + fexp2(C2 * gG));
      const float cn = fmaf(sf, c_old, si * tg);
      const float so = frcp(1.f + fexp2(-L2E * go));
      const float tc = 1.f - 2.f * frcp(1.f + fexp2(C2 * cn));
      const float hn = so * tc;
      if ((lane & 15) == 0) {   // one writer per hidden unit
        hcp[p ^ 1][k_de >> 4][k_de & 15]       = hn;
        hcp[p ^ 1][4 + (k_de >> 4)][k_de & 15] = cn;
#pragma unroll
        for (int q2 = 0; q2 < 4; ++q2) hrep[p ^ 1][q2][k_de] = hn;
        hbuf[t][k_de] = hn;
      }
    }
    __syncthreads();
    p ^= 1;
  }

  // ---------------- bulk flush of outputs -----------------------------------
#pragma unroll
  for (int i = 0; i < 4; ++i) {
    const int f = i * 1024 + tid;
    const int t = f >> 5, c = (f & 31) << 2;
    *reinterpret_cast<float4*>(out + b * (NT * ND) + t * ND + c) =
        *reinterpret_cast<const float4*>(&xh[t][c]);
  }
  float* out2 = out + NB * (NT * ND) + b * (NT * NH);
#pragma unroll
  for (int i = 0; i < 2; ++i) {
    const int f = i * 1024 + tid;
    const int t = f >> 4, c = (f & 15) << 2;
    *reinterpret_cast<float4*>(out2 + t * NH + c) =
        *reinterpret_cast<const float4*>(&hbuf[t][c]);
  }
}

extern "C" void kernel_launch(void* const* d_in, const int* in_sizes, int n_in,
                              void* d_out, int out_size, void* d_ws, size_t ws_size,
                              hipStream_t stream) {
  const float* x    = (const float*)d_in[0];
  const float* Wehs = (const float*)d_in[1];
  const float* behs = (const float*)d_in[2];
  const float* Ue   = (const float*)d_in[3];
  const float* Ueb  = (const float*)d_in[4];
  const float* vew  = (const float*)d_in[5];
  // d_in[6] = v_e_b: constant shift before softmax -> no effect, unused.
  const float* Wih  = (const float*)d_in[7];
  const float* Whh  = (const float*)d_in[8];
  const float* bih  = (const float*)d_in[9];
  const float* bhh  = (const float*)d_in[10];
  float* out = (float*)d_out;

  darnn_enc<<<NB, NTH, 0, stream>>>(x, Wehs, behs, Ue, Ueb, vew, Wih, Whh, bih, bhh, out);
}